// Round 1
// baseline (390.696 us; speedup 1.0000x reference)
//
#include <hip/hip_runtime.h>
#include <cmath>

#define C_DIM 256
#define E_DIM 128
#define S_DIM 4096

typedef __bf16 bf16x8 __attribute__((ext_vector_type(8)));
typedef float  f32x4  __attribute__((ext_vector_type(4)));
typedef short  s16x8  __attribute__((ext_vector_type(8)));
typedef short  s16x4  __attribute__((ext_vector_type(4)));

__device__ __forceinline__ unsigned short f2bf(float f) {
  union { float f; unsigned u; } v; v.f = f;
  unsigned r = v.u + 0x7FFFu + ((v.u >> 16) & 1u);
  return (unsigned short)(r >> 16);
}
__device__ __forceinline__ float bf2f(unsigned short b) {
  union { unsigned u; float f; } v; v.u = ((unsigned)b) << 16;
  return v.f;
}

// ---------------------------------------------------------------------------
// Kernel 1: channel mixing. Q[n,s,e] = sum_c Wth[e,c] x[n,c,s]; same for K.
// Also emits bf16 copy of x (serves as V^T[c][t] for the PV step).
// grid: N * (S/32) = 512 blocks, 256 threads.
// ---------------------------------------------------------------------------
__global__ __launch_bounds__(256) void mix_kernel(
    const float* __restrict__ x, const float* __restrict__ Wth,
    const float* __restrict__ Wph, short* __restrict__ Qg,
    short* __restrict__ Kg, short* __restrict__ Xb) {
  __shared__ float lx[C_DIM * 32];   // [c][s] fp32 tile, 32 KB
  int bid = blockIdx.x;
  int n = bid >> 7, s0 = (bid & 127) * 32;
  int tid = threadIdx.x;

  { // stage x tile (coalesced float4) + write bf16 copy of x
    int c0 = tid >> 3, f4 = tid & 7;
    #pragma unroll
    for (int i = 0; i < 8; ++i) {
      int c = c0 + 32 * i;
      const float4* src =
          (const float4*)(x + ((size_t)n * C_DIM + c) * S_DIM + s0) + f4;
      float4 v = *src;
      *(float4*)(lx + c * 32 + f4 * 4) = v;
      s16x4 b;
      b[0] = (short)f2bf(v.x); b[1] = (short)f2bf(v.y);
      b[2] = (short)f2bf(v.z); b[3] = (short)f2bf(v.w);
      *(s16x4*)(Xb + ((size_t)n * C_DIM + c) * S_DIM + s0 + f4 * 4) = b;
    }
  }
  __syncthreads();

  int s = tid & 31, eg = tid >> 5;   // eg in 0..7 -> 16 e-rows each
  float accQ[16], accK[16];
  #pragma unroll
  for (int e = 0; e < 16; ++e) { accQ[e] = 0.f; accK[e] = 0.f; }

  for (int c = 0; c < C_DIM; c += 4) {
    float xs0 = lx[(c + 0) * 32 + s], xs1 = lx[(c + 1) * 32 + s];
    float xs2 = lx[(c + 2) * 32 + s], xs3 = lx[(c + 3) * 32 + s];
    #pragma unroll
    for (int e = 0; e < 16; ++e) {
      int row = eg * 16 + e;
      float4 wq = *(const float4*)(Wth + row * C_DIM + c);
      float4 wk = *(const float4*)(Wph + row * C_DIM + c);
      accQ[e] += wq.x * xs0 + wq.y * xs1 + wq.z * xs2 + wq.w * xs3;
      accK[e] += wk.x * xs0 + wk.y * xs1 + wk.z * xs2 + wk.w * xs3;
    }
  }
  __syncthreads();

  // pack results into LDS bf16 tiles [32 s][128 e] (swizzled), then coalesced store
  short* Qt = (short*)lx;
  short* Kt = Qt + 32 * E_DIM;
  #pragma unroll
  for (int k = 0; k < 8; ++k) {
    unsigned pq = (unsigned)f2bf(accQ[2 * k]) | ((unsigned)f2bf(accQ[2 * k + 1]) << 16);
    unsigned pk = (unsigned)f2bf(accK[2 * k]) | ((unsigned)f2bf(accK[2 * k + 1]) << 16);
    int off = s * 256 + ((eg * 32 + k * 4) ^ ((s & 7) << 4));
    *(unsigned*)((char*)Qt + off) = pq;
    *(unsigned*)((char*)Kt + off) = pk;
  }
  __syncthreads();
  int sr = tid >> 4, ch = tid & 15;
  #pragma unroll
  for (int i = 0; i < 2; ++i) {
    int r = sr + 16 * i;
    int off = r * 256 + ((ch * 16) ^ ((r & 7) << 4));
    s16x8 vq = *(const s16x8*)((char*)Qt + off);
    s16x8 vk = *(const s16x8*)((char*)Kt + off);
    *(s16x8*)(Qg + ((size_t)n * S_DIM + s0 + r) * E_DIM + ch * 8) = vq;
    *(s16x8*)(Kg + ((size_t)n * S_DIM + s0 + r) * E_DIM + ch * 8) = vk;
  }
}

// ---------------------------------------------------------------------------
// Kernel 2: flash attention (no-max-needed softmax: logits are O(0.1)).
// grid: N * (S/64) = 256 blocks, 4 waves. Waves COOPERATE on one 64-row Q
// tile: wave w computes QK^T t-quarter w and PV c-quarter w (minimizes LDS
// re-reads). y[n,s,c] written bf16.
// ---------------------------------------------------------------------------
__global__ __launch_bounds__(256, 1) void attn_kernel(
    const short* __restrict__ Qg, const short* __restrict__ Kg,
    const short* __restrict__ Xb, short* __restrict__ Yg, float scale) {
  __shared__ short lK[64 * E_DIM];   // [t][e]  swizzled, 16 KB
  __shared__ short lV[C_DIM * 64];   // [c][t]  swizzled, 32 KB (V^T layout)
  __shared__ short lP[64 * 64];      // [q][t]  swizzled,  8 KB, shared

  int bid = blockIdx.x;
  int n = bid >> 6, s0 = (bid & 63) * 64;
  int tid = threadIdx.x;
  int wid = tid >> 6, lane = tid & 63;
  int l15 = lane & 15, l4 = lane >> 4;

  // Q fragments for ALL 64 q-rows of the block (per wave, in registers)
  bf16x8 qf[4][4];
  #pragma unroll
  for (int qs = 0; qs < 4; ++qs) {
    const short* qp = Qg + ((size_t)n * S_DIM + s0 + qs * 16 + l15) * E_DIM + l4 * 8;
    #pragma unroll
    for (int ec = 0; ec < 4; ++ec) qf[qs][ec] = *(const bf16x8*)(qp + ec * 32);
  }

  const f32x4 fzero = {0.f, 0.f, 0.f, 0.f};
  f32x4 acc[4][4];                       // [qsub][ct] ; c = wid*64 + ct*16 + l15
  #pragma unroll
  for (int a = 0; a < 4; ++a)
    #pragma unroll
    for (int b = 0; b < 4; ++b) acc[a][b] = fzero;
  float lsum[4][4];
  #pragma unroll
  for (int a = 0; a < 4; ++a)
    #pragma unroll
    for (int b = 0; b < 4; ++b) lsum[a][b] = 0.f;

  const short* Kbase = Kg + (size_t)n * S_DIM * E_DIM;
  const short* Vbase = Xb + (size_t)n * (size_t)C_DIM * S_DIM;
  int kr = tid >> 4, kc = tid & 15;   // K stage: 64 rows x 16 chunks
  int vr = tid >> 3, vc = tid & 7;    // V stage: 256 rows x 8 chunks

  // register prefetch of tile t0=0
  s16x8 kpre[4], vpre[8];
  #pragma unroll
  for (int i = 0; i < 4; ++i)
    kpre[i] = *(const s16x8*)(Kbase + (size_t)(kr + 16 * i) * E_DIM + kc * 8);
  #pragma unroll
  for (int i = 0; i < 8; ++i)
    vpre[i] = *(const s16x8*)(Vbase + (size_t)(vr + 32 * i) * S_DIM + vc * 8);

  for (int t0 = 0; t0 < S_DIM; t0 += 64) {
    // commit staged tile to LDS (XOR-swizzled rows)
    #pragma unroll
    for (int i = 0; i < 4; ++i) {
      int r = kr + 16 * i;
      *(s16x8*)((char*)lK + r * 256 + ((kc * 16) ^ ((r & 7) << 4))) = kpre[i];
    }
    #pragma unroll
    for (int i = 0; i < 8; ++i) {
      int c = vr + 32 * i;
      *(s16x8*)((char*)lV + c * 128 + ((vc * 16) ^ ((c & 7) << 4))) = vpre[i];
    }
    __syncthreads();

    // prefetch next tile (stays in flight across compute)
    if (t0 + 64 < S_DIM) {
      #pragma unroll
      for (int i = 0; i < 4; ++i)
        kpre[i] = *(const s16x8*)(Kbase + (size_t)(t0 + 64 + kr + 16 * i) * E_DIM + kc * 8);
      #pragma unroll
      for (int i = 0; i < 8; ++i)
        vpre[i] = *(const s16x8*)(Vbase + (size_t)(vr + 32 * i) * S_DIM + (t0 + 64) + vc * 8);
    }

    // QK^T for this wave's t-quarter (t = wid*16 + col)
    f32x4 sc[4];
    #pragma unroll
    for (int qs = 0; qs < 4; ++qs) sc[qs] = fzero;
    {
      int trow = wid * 16 + l15;
      int rbase = trow * 256, swz = (trow & 7) << 4;
      #pragma unroll
      for (int ec = 0; ec < 4; ++ec) {
        bf16x8 kf = *(const bf16x8*)((char*)lK + rbase + ((ec * 64 + l4 * 16) ^ swz));
        #pragma unroll
        for (int qs = 0; qs < 4; ++qs)
          sc[qs] = __builtin_amdgcn_mfma_f32_16x16x32_bf16(qf[qs][ec], kf, sc[qs], 0, 0, 0);
      }
    }

    // exp2 (max-free softmax numerator), row-sum partials, stash P bf16
    #pragma unroll
    for (int qs = 0; qs < 4; ++qs) {
      #pragma unroll
      for (int r = 0; r < 4; ++r) {
        int q = qs * 16 + l4 * 4 + r;
        float p = __builtin_amdgcn_exp2f(sc[qs][r] * scale);
        lsum[qs][r] += p;
        *(unsigned short*)((char*)lP + q * 128 +
                           ((wid * 32 + l15 * 2) ^ ((q & 7) << 4))) = f2bf(p);
      }
    }
    __syncthreads();   // P complete across waves

    // PV for this wave's c-quarter
    #pragma unroll
    for (int tk = 0; tk < 2; ++tk) {
      bf16x8 pf[4];
      #pragma unroll
      for (int qs = 0; qs < 4; ++qs) {
        int prow = qs * 16 + l15;
        pf[qs] = *(const bf16x8*)((char*)lP + prow * 128 +
                                  ((tk * 64 + l4 * 16) ^ ((prow & 7) << 4)));
      }
      #pragma unroll
      for (int ct = 0; ct < 4; ++ct) {
        int crow = wid * 64 + ct * 16 + l15;
        bf16x8 vf = *(const bf16x8*)((char*)lV + crow * 128 +
                                     ((tk * 64 + l4 * 16) ^ ((crow & 7) << 4)));
        #pragma unroll
        for (int qs = 0; qs < 4; ++qs)
          acc[qs][ct] =
              __builtin_amdgcn_mfma_f32_16x16x32_bf16(pf[qs], vf, acc[qs][ct], 0, 0, 0);
      }
    }
    __syncthreads();   // done reading lK/lV/lP before next overwrite
  }

  // ---- epilogue: denominators, normalize, transpose-write y ----
  float* lsred = (float*)lP;   // [wave][64 q] fp32 partial sums
  #pragma unroll
  for (int qs = 0; qs < 4; ++qs)
    #pragma unroll
    for (int r = 0; r < 4; ++r) {
      float v = lsum[qs][r];
      v += __shfl_xor(v, 1); v += __shfl_xor(v, 2);
      v += __shfl_xor(v, 4); v += __shfl_xor(v, 8);
      lsum[qs][r] = v;
    }
  if (l15 == 0) {
    #pragma unroll
    for (int qs = 0; qs < 4; ++qs)
      #pragma unroll
      for (int r = 0; r < 4; ++r)
        lsred[wid * 64 + qs * 16 + l4 * 4 + r] = lsum[qs][r];
  }
  __syncthreads();

  // write normalized y into lV reused as [64 q][256 c] bf16 (swizzled)
  #pragma unroll
  for (int qs = 0; qs < 4; ++qs) {
    #pragma unroll
    for (int r = 0; r < 4; ++r) {
      int q = qs * 16 + l4 * 4 + r;
      float tot = lsred[q] + lsred[64 + q] + lsred[128 + q] + lsred[192 + q];
      float rl = 1.0f / tot;
      #pragma unroll
      for (int ct = 0; ct < 4; ++ct) {
        int c = wid * 64 + ct * 16 + l15;
        *(unsigned short*)((char*)lV + q * 512 + ((c * 2) ^ ((q & 7) << 4))) =
            f2bf(acc[qs][ct][r] * rl);
      }
    }
  }
  __syncthreads();
  int yr = tid >> 5, ych = tid & 31;
  #pragma unroll
  for (int i = 0; i < 8; ++i) {
    int rr = yr + 8 * i;
    s16x8 v = *(const s16x8*)((char*)lV + rr * 512 + ((ych * 16) ^ ((rr & 7) << 4)));
    *(s16x8*)(Yg + ((size_t)n * S_DIM + s0 + rr) * C_DIM + ych * 8) = v;
  }
}

// ---------------------------------------------------------------------------
// Kernel 3: out[n,o,s] = x[n,o,s] + sum_c Wp[o,c] * y[n,s,c]
// grid: N * (S/32) = 512 blocks, 256 threads.
// ---------------------------------------------------------------------------
__global__ __launch_bounds__(256) void proj_kernel(
    const short* __restrict__ Yg, const float* __restrict__ Wp,
    const float* __restrict__ x, float* __restrict__ out) {
  __shared__ short ly[32 * C_DIM];   // 16 KB, swizzled [s][c]
  int bid = blockIdx.x;
  int n = bid >> 7, s0 = (bid & 127) * 32;
  int tid = threadIdx.x;
  {
    int sr = tid >> 5, ch = tid & 31;
    #pragma unroll
    for (int i = 0; i < 4; ++i) {
      int r = sr + 8 * i;
      s16x8 v = *(const s16x8*)(Yg + ((size_t)n * S_DIM + s0 + r) * C_DIM + ch * 8);
      *(s16x8*)((char*)ly + r * 512 + ((ch * 16) ^ ((r & 7) << 4))) = v;
    }
  }
  __syncthreads();

  int s = tid & 31, og = tid >> 5;   // og in 0..7 -> 32 output channels each
  float acc[32];
  #pragma unroll
  for (int o = 0; o < 32; ++o) acc[o] = 0.f;

  for (int c = 0; c < C_DIM; c += 8) {
    s16x8 yv = *(const s16x8*)((char*)ly + s * 512 + ((c * 2) ^ ((s & 7) << 4)));
    float yf[8];
    #pragma unroll
    for (int j = 0; j < 8; ++j) yf[j] = bf2f((unsigned short)yv[j]);
    #pragma unroll
    for (int o = 0; o < 32; ++o) {
      const float* wrow = Wp + (og * 32 + o) * C_DIM + c;
      float4 w0 = *(const float4*)(wrow);
      float4 w1 = *(const float4*)(wrow + 4);
      acc[o] += w0.x * yf[0] + w0.y * yf[1] + w0.z * yf[2] + w0.w * yf[3] +
                w1.x * yf[4] + w1.y * yf[5] + w1.z * yf[6] + w1.w * yf[7];
    }
  }
  #pragma unroll
  for (int o = 0; o < 32; ++o) {
    size_t idx = ((size_t)n * C_DIM + og * 32 + o) * (size_t)S_DIM + s0 + s;
    out[idx] = x[idx] + acc[o];
  }
}

// ---------------------------------------------------------------------------
extern "C" void kernel_launch(void* const* d_in, const int* in_sizes, int n_in,
                              void* d_out, int out_size, void* d_ws, size_t ws_size,
                              hipStream_t stream) {
  const float* x   = (const float*)d_in[0];
  const float* Wth = (const float*)d_in[1];
  const float* Wph = (const float*)d_in[2];
  const float* Wpr = (const float*)d_in[3];
  float* out = (float*)d_out;

  short* q_ws  = (short*)d_ws;                              // 4 MB  [N,S,E]
  short* k_ws  = q_ws  + (size_t)4 * S_DIM * E_DIM;         // 4 MB  [N,S,E]
  short* xb_ws = k_ws  + (size_t)4 * S_DIM * E_DIM;         // 8 MB  [N,C,S]
  short* y_ws  = xb_ws + (size_t)4 * C_DIM * S_DIM;         // 8 MB  [N,S,C]

  float scale = 1.4426950408889634f / sqrtf(128.0f);        // log2(e)/sqrt(E)

  mix_kernel<<<512, 256, 0, stream>>>(x, Wth, Wph, q_ws, k_ws, xb_ws);
  attn_kernel<<<256, 256, 0, stream>>>(q_ws, k_ws, xb_ws, y_ws, scale);
  proj_kernel<<<512, 256, 0, stream>>>(y_ws, Wpr, x, out);
}

// Round 2
// 148.057 us; speedup vs baseline: 2.6388x; 2.6388x over previous
//
#include <hip/hip_runtime.h>
#include <cmath>

#define C_DIM 256
#define E_DIM 128
#define S_DIM 4096

typedef __bf16 bf16x8 __attribute__((ext_vector_type(8)));
typedef float  f32x4  __attribute__((ext_vector_type(4)));
typedef short  s16x8  __attribute__((ext_vector_type(8)));
typedef short  s16x4  __attribute__((ext_vector_type(4)));

__device__ __forceinline__ unsigned short f2bf(float f) {
  union { float f; unsigned u; } v; v.f = f;
  unsigned r = v.u + 0x7FFFu + ((v.u >> 16) & 1u);
  return (unsigned short)(r >> 16);
}

// ---------------------------------------------------------------------------
// Kernel 0: cast the three weight matrices fp32 -> bf16 into ws.
// Layout in Wb: [Wth 32768][Wph 32768][Wproj 65536] shorts.
// grid 128 x 256, 4 elems/thread.
// ---------------------------------------------------------------------------
__global__ __launch_bounds__(256) void cast_w_kernel(
    const float* __restrict__ Wth, const float* __restrict__ Wph,
    const float* __restrict__ Wpr, short* __restrict__ Wb) {
  int t = blockIdx.x * 256 + threadIdx.x;
  int i = t * 4;
  const float* src; int j;
  if (i < 32768)      { src = Wth; j = i; }
  else if (i < 65536) { src = Wph; j = i - 32768; }
  else                { src = Wpr; j = i - 65536; }
  float4 v = *(const float4*)(src + j);
  s16x4 o;
  o[0] = (short)f2bf(v.x); o[1] = (short)f2bf(v.y);
  o[2] = (short)f2bf(v.z); o[3] = (short)f2bf(v.w);
  *(s16x4*)(Wb + i) = o;
}

// ---------------------------------------------------------------------------
// Kernel 1 (MFMA): Q[s,e] = sum_c Wth[e,c] x[c,s]; K likewise. Emits bf16 x.
// Block: 128 e x 32 s, 4 waves (wave w -> e quarter). K = C = 256.
// A-frags: W bf16 rows from global (L2). B-frags: x^T tile in swizzled LDS.
// grid: N * (S/32) = 512 blocks.
// ---------------------------------------------------------------------------
__global__ __launch_bounds__(256) void mix_kernel(
    const float* __restrict__ x, const short* __restrict__ Wb,
    short* __restrict__ Qg, short* __restrict__ Kg, short* __restrict__ Xb) {
  __shared__ short lxT[32 * C_DIM];   // [s][c] bf16, swizzled, 16 KB
  int bid = blockIdx.x;
  int n = bid >> 7, s0 = (bid & 127) * 32;
  int tid = threadIdx.x;
  int wid = tid >> 6, lane = tid & 63, l15 = lane & 15, l4 = lane >> 4;

  // ---- stage x^T tile (transpose via row-pair dword packing) + emit Xb ----
  {
    int cp = tid >> 1, su = tid & 1;     // rows (2cp, 2cp+1), s-half su*16
    const float* r0 = x + ((size_t)n * C_DIM + 2 * cp) * S_DIM + s0 + su * 16;
    const float* r1 = r0 + S_DIM;
    float a0[16], a1[16];
    #pragma unroll
    for (int j = 0; j < 4; ++j) {
      *(float4*)(a0 + 4 * j) = *(const float4*)(r0 + 4 * j);
      *(float4*)(a1 + 4 * j) = *(const float4*)(r1 + 4 * j);
    }
    short b0[16], b1[16];
    #pragma unroll
    for (int j = 0; j < 16; ++j) {
      b0[j] = (short)f2bf(a0[j]);
      b1[j] = (short)f2bf(a1[j]);
    }
    short* xb0 = Xb + ((size_t)n * C_DIM + 2 * cp) * S_DIM + s0 + su * 16;
    *(s16x8*)(xb0)             = *(s16x8*)(b0);
    *(s16x8*)(xb0 + 8)         = *(s16x8*)(b0 + 8);
    *(s16x8*)(xb0 + S_DIM)     = *(s16x8*)(b1);
    *(s16x8*)(xb0 + S_DIM + 8) = *(s16x8*)(b1 + 8);
    #pragma unroll
    for (int j = 0; j < 16; ++j) {
      int s = su * 16 + j;
      unsigned d = (unsigned)(unsigned short)b0[j] |
                   ((unsigned)(unsigned short)b1[j] << 16);
      // element (s,c) lives at byte s*512 + ((c*2) ^ ((s&7)<<4)); c = 2cp
      *(unsigned*)((char*)lxT + s * 512 + ((4 * cp) ^ ((s & 7) << 4))) = d;
    }
  }
  __syncthreads();

  // ---- MFMA main: wave w owns e in [w*32, w*32+32), both GEMMs ----
  const short* Wq = Wb;
  const short* Wk = Wb + 32768;
  const f32x4 fzero = {0.f, 0.f, 0.f, 0.f};
  f32x4 accQ[2][2], accK[2][2];   // [mf(e)][nf(s)]
  #pragma unroll
  for (int a = 0; a < 2; ++a)
    #pragma unroll
    for (int b = 0; b < 2; ++b) { accQ[a][b] = fzero; accK[a][b] = fzero; }

  #pragma unroll 2
  for (int kk = 0; kk < 8; ++kk) {
    bf16x8 bfr[2];
    #pragma unroll
    for (int nf = 0; nf < 2; ++nf) {
      int s = nf * 16 + l15;
      bfr[nf] = *(const bf16x8*)((char*)lxT + s * 512 +
                                 ((kk * 64 + l4 * 16) ^ ((s & 7) << 4)));
    }
    #pragma unroll
    for (int mf = 0; mf < 2; ++mf) {
      int e = wid * 32 + mf * 16 + l15;
      bf16x8 aq = *(const bf16x8*)(Wq + e * C_DIM + kk * 32 + l4 * 8);
      bf16x8 ak = *(const bf16x8*)(Wk + e * C_DIM + kk * 32 + l4 * 8);
      #pragma unroll
      for (int nf = 0; nf < 2; ++nf) {
        accQ[mf][nf] = __builtin_amdgcn_mfma_f32_16x16x32_bf16(aq, bfr[nf], accQ[mf][nf], 0, 0, 0);
        accK[mf][nf] = __builtin_amdgcn_mfma_f32_16x16x32_bf16(ak, bfr[nf], accK[mf][nf], 0, 0, 0);
      }
    }
  }

  // ---- store: D row = e (4 consecutive in regs), col = s ----
  #pragma unroll
  for (int mf = 0; mf < 2; ++mf) {
    #pragma unroll
    for (int nf = 0; nf < 2; ++nf) {
      int e = wid * 32 + mf * 16 + l4 * 4;
      int s = s0 + nf * 16 + l15;
      s16x4 pq, pk;
      #pragma unroll
      for (int r = 0; r < 4; ++r) {
        pq[r] = (short)f2bf(accQ[mf][nf][r]);
        pk[r] = (short)f2bf(accK[mf][nf][r]);
      }
      *(s16x4*)(Qg + ((size_t)n * S_DIM + s) * E_DIM + e) = pq;
      *(s16x4*)(Kg + ((size_t)n * S_DIM + s) * E_DIM + e) = pk;
    }
  }
}

// ---------------------------------------------------------------------------
// Kernel 2: flash attention (no-max softmax: logits are O(0.1)). UNCHANGED.
// ---------------------------------------------------------------------------
__global__ __launch_bounds__(256, 1) void attn_kernel(
    const short* __restrict__ Qg, const short* __restrict__ Kg,
    const short* __restrict__ Xb, short* __restrict__ Yg, float scale) {
  __shared__ short lK[64 * E_DIM];
  __shared__ short lV[C_DIM * 64];
  __shared__ short lP[64 * 64];

  int bid = blockIdx.x;
  int n = bid >> 6, s0 = (bid & 63) * 64;
  int tid = threadIdx.x;
  int wid = tid >> 6, lane = tid & 63;
  int l15 = lane & 15, l4 = lane >> 4;

  bf16x8 qf[4][4];
  #pragma unroll
  for (int qs = 0; qs < 4; ++qs) {
    const short* qp = Qg + ((size_t)n * S_DIM + s0 + qs * 16 + l15) * E_DIM + l4 * 8;
    #pragma unroll
    for (int ec = 0; ec < 4; ++ec) qf[qs][ec] = *(const bf16x8*)(qp + ec * 32);
  }

  const f32x4 fzero = {0.f, 0.f, 0.f, 0.f};
  f32x4 acc[4][4];
  #pragma unroll
  for (int a = 0; a < 4; ++a)
    #pragma unroll
    for (int b = 0; b < 4; ++b) acc[a][b] = fzero;
  float lsum[4][4];
  #pragma unroll
  for (int a = 0; a < 4; ++a)
    #pragma unroll
    for (int b = 0; b < 4; ++b) lsum[a][b] = 0.f;

  const short* Kbase = Kg + (size_t)n * S_DIM * E_DIM;
  const short* Vbase = Xb + (size_t)n * (size_t)C_DIM * S_DIM;
  int kr = tid >> 4, kc = tid & 15;
  int vr = tid >> 3, vc = tid & 7;

  s16x8 kpre[4], vpre[8];
  #pragma unroll
  for (int i = 0; i < 4; ++i)
    kpre[i] = *(const s16x8*)(Kbase + (size_t)(kr + 16 * i) * E_DIM + kc * 8);
  #pragma unroll
  for (int i = 0; i < 8; ++i)
    vpre[i] = *(const s16x8*)(Vbase + (size_t)(vr + 32 * i) * S_DIM + vc * 8);

  for (int t0 = 0; t0 < S_DIM; t0 += 64) {
    #pragma unroll
    for (int i = 0; i < 4; ++i) {
      int r = kr + 16 * i;
      *(s16x8*)((char*)lK + r * 256 + ((kc * 16) ^ ((r & 7) << 4))) = kpre[i];
    }
    #pragma unroll
    for (int i = 0; i < 8; ++i) {
      int c = vr + 32 * i;
      *(s16x8*)((char*)lV + c * 128 + ((vc * 16) ^ ((c & 7) << 4))) = vpre[i];
    }
    __syncthreads();

    if (t0 + 64 < S_DIM) {
      #pragma unroll
      for (int i = 0; i < 4; ++i)
        kpre[i] = *(const s16x8*)(Kbase + (size_t)(t0 + 64 + kr + 16 * i) * E_DIM + kc * 8);
      #pragma unroll
      for (int i = 0; i < 8; ++i)
        vpre[i] = *(const s16x8*)(Vbase + (size_t)(vr + 32 * i) * S_DIM + (t0 + 64) + vc * 8);
    }

    f32x4 sc[4];
    #pragma unroll
    for (int qs = 0; qs < 4; ++qs) sc[qs] = fzero;
    {
      int trow = wid * 16 + l15;
      int rbase = trow * 256, swz = (trow & 7) << 4;
      #pragma unroll
      for (int ec = 0; ec < 4; ++ec) {
        bf16x8 kf = *(const bf16x8*)((char*)lK + rbase + ((ec * 64 + l4 * 16) ^ swz));
        #pragma unroll
        for (int qs = 0; qs < 4; ++qs)
          sc[qs] = __builtin_amdgcn_mfma_f32_16x16x32_bf16(qf[qs][ec], kf, sc[qs], 0, 0, 0);
      }
    }

    #pragma unroll
    for (int qs = 0; qs < 4; ++qs) {
      #pragma unroll
      for (int r = 0; r < 4; ++r) {
        int q = qs * 16 + l4 * 4 + r;
        float p = __builtin_amdgcn_exp2f(sc[qs][r] * scale);
        lsum[qs][r] += p;
        *(unsigned short*)((char*)lP + q * 128 +
                           ((wid * 32 + l15 * 2) ^ ((q & 7) << 4))) = f2bf(p);
      }
    }
    __syncthreads();

    #pragma unroll
    for (int tk = 0; tk < 2; ++tk) {
      bf16x8 pf[4];
      #pragma unroll
      for (int qs = 0; qs < 4; ++qs) {
        int prow = qs * 16 + l15;
        pf[qs] = *(const bf16x8*)((char*)lP + prow * 128 +
                                  ((tk * 64 + l4 * 16) ^ ((prow & 7) << 4)));
      }
      #pragma unroll
      for (int ct = 0; ct < 4; ++ct) {
        int crow = wid * 64 + ct * 16 + l15;
        bf16x8 vf = *(const bf16x8*)((char*)lV + crow * 128 +
                                     ((tk * 64 + l4 * 16) ^ ((crow & 7) << 4)));
        #pragma unroll
        for (int qs = 0; qs < 4; ++qs)
          acc[qs][ct] =
              __builtin_amdgcn_mfma_f32_16x16x32_bf16(pf[qs], vf, acc[qs][ct], 0, 0, 0);
      }
    }
    __syncthreads();
  }

  float* lsred = (float*)lP;
  #pragma unroll
  for (int qs = 0; qs < 4; ++qs)
    #pragma unroll
    for (int r = 0; r < 4; ++r) {
      float v = lsum[qs][r];
      v += __shfl_xor(v, 1); v += __shfl_xor(v, 2);
      v += __shfl_xor(v, 4); v += __shfl_xor(v, 8);
      lsum[qs][r] = v;
    }
  if (l15 == 0) {
    #pragma unroll
    for (int qs = 0; qs < 4; ++qs)
      #pragma unroll
      for (int r = 0; r < 4; ++r)
        lsred[wid * 64 + qs * 16 + l4 * 4 + r] = lsum[qs][r];
  }
  __syncthreads();

  #pragma unroll
  for (int qs = 0; qs < 4; ++qs) {
    #pragma unroll
    for (int r = 0; r < 4; ++r) {
      int q = qs * 16 + l4 * 4 + r;
      float tot = lsred[q] + lsred[64 + q] + lsred[128 + q] + lsred[192 + q];
      float rl = 1.0f / tot;
      #pragma unroll
      for (int ct = 0; ct < 4; ++ct) {
        int c = wid * 64 + ct * 16 + l15;
        *(unsigned short*)((char*)lV + q * 512 + ((c * 2) ^ ((q & 7) << 4))) =
            f2bf(acc[qs][ct][r] * rl);
      }
    }
  }
  __syncthreads();
  int yr = tid >> 5, ych = tid & 31;
  #pragma unroll
  for (int i = 0; i < 8; ++i) {
    int rr = yr + 8 * i;
    s16x8 v = *(const s16x8*)((char*)lV + rr * 512 + ((ych * 16) ^ ((rr & 7) << 4)));
    *(s16x8*)(Yg + ((size_t)n * S_DIM + s0 + rr) * C_DIM + ych * 8) = v;
  }
}

// ---------------------------------------------------------------------------
// Kernel 3 (MFMA, zero LDS): out[o,s] = x[o,s] + sum_c Wp[o,c] y[s,c]
// A = y rows (M = s), B = Wp rows (N = o). D rows = 4 consecutive s -> float4.
// Block: 32 s x 256 o, 4 waves (wave w -> o range w*64). grid 512.
// ---------------------------------------------------------------------------
__global__ __launch_bounds__(256) void proj_kernel(
    const short* __restrict__ Yg, const short* __restrict__ Wpb,
    const float* __restrict__ x, float* __restrict__ out) {
  int bid = blockIdx.x;
  int n = bid >> 7, s0 = (bid & 127) * 32;
  int tid = threadIdx.x;
  int wid = tid >> 6, lane = tid & 63, l15 = lane & 15, l4 = lane >> 4;

  const f32x4 fzero = {0.f, 0.f, 0.f, 0.f};
  f32x4 acc[2][4];   // [mf(s)][nf(o)]
  #pragma unroll
  for (int a = 0; a < 2; ++a)
    #pragma unroll
    for (int b = 0; b < 4; ++b) acc[a][b] = fzero;

  const short* ybase = Yg + (size_t)n * S_DIM * C_DIM;

  #pragma unroll 2
  for (int kk = 0; kk < 8; ++kk) {
    bf16x8 af[2];
    #pragma unroll
    for (int mf = 0; mf < 2; ++mf)
      af[mf] = *(const bf16x8*)(ybase + (size_t)(s0 + mf * 16 + l15) * C_DIM +
                                kk * 32 + l4 * 8);
    #pragma unroll
    for (int nf = 0; nf < 4; ++nf) {
      int o = wid * 64 + nf * 16 + l15;
      bf16x8 bfr = *(const bf16x8*)(Wpb + o * C_DIM + kk * 32 + l4 * 8);
      #pragma unroll
      for (int mf = 0; mf < 2; ++mf)
        acc[mf][nf] = __builtin_amdgcn_mfma_f32_16x16x32_bf16(af[mf], bfr, acc[mf][nf], 0, 0, 0);
    }
  }

  #pragma unroll
  for (int mf = 0; mf < 2; ++mf) {
    #pragma unroll
    for (int nf = 0; nf < 4; ++nf) {
      int o = wid * 64 + nf * 16 + l15;
      size_t idx = ((size_t)n * C_DIM + o) * (size_t)S_DIM + s0 + mf * 16 + l4 * 4;
      float4 xv = *(const float4*)(x + idx);
      float4 r;
      r.x = xv.x + acc[mf][nf][0];
      r.y = xv.y + acc[mf][nf][1];
      r.z = xv.z + acc[mf][nf][2];
      r.w = xv.w + acc[mf][nf][3];
      *(float4*)(out + idx) = r;
    }
  }
}

// ---------------------------------------------------------------------------
extern "C" void kernel_launch(void* const* d_in, const int* in_sizes, int n_in,
                              void* d_out, int out_size, void* d_ws, size_t ws_size,
                              hipStream_t stream) {
  const float* x   = (const float*)d_in[0];
  const float* Wth = (const float*)d_in[1];
  const float* Wph = (const float*)d_in[2];
  const float* Wpr = (const float*)d_in[3];
  float* out = (float*)d_out;

  short* q_ws  = (short*)d_ws;                              // 4 MB  [N,S,E]
  short* k_ws  = q_ws  + (size_t)4 * S_DIM * E_DIM;         // 4 MB  [N,S,E]
  short* xb_ws = k_ws  + (size_t)4 * S_DIM * E_DIM;         // 8 MB  [N,C,S]
  short* y_ws  = xb_ws + (size_t)4 * C_DIM * S_DIM;         // 8 MB  [N,S,C]
  short* wb_ws = y_ws  + (size_t)4 * S_DIM * C_DIM;         // 256 KB bf16 weights

  float scale = 1.4426950408889634f / sqrtf(128.0f);        // log2(e)/sqrt(E)

  cast_w_kernel<<<128, 256, 0, stream>>>(Wth, Wph, Wpr, wb_ws);
  mix_kernel<<<512, 256, 0, stream>>>(x, wb_ws, q_ws, k_ws, xb_ws);
  attn_kernel<<<256, 256, 0, stream>>>(q_ws, k_ws, xb_ws, y_ws, scale);
  proj_kernel<<<512, 256, 0, stream>>>(y_ws, wb_ws + 65536, x, out);
}

// Round 3
// 136.853 us; speedup vs baseline: 2.8549x; 1.0819x over previous
//
#include <hip/hip_runtime.h>
#include <cmath>

#define C_DIM 256
#define E_DIM 128
#define S_DIM 4096

typedef __bf16 bf16x8 __attribute__((ext_vector_type(8)));
typedef float  f32x4  __attribute__((ext_vector_type(4)));
typedef short  s16x8  __attribute__((ext_vector_type(8)));
typedef short  s16x4  __attribute__((ext_vector_type(4)));

__device__ __forceinline__ unsigned short f2bf(float f) {
  union { float f; unsigned u; } v; v.f = f;
  unsigned r = v.u + 0x7FFFu + ((v.u >> 16) & 1u);
  return (unsigned short)(r >> 16);
}
__device__ __forceinline__ bf16x8 as_bf(s16x8 v) {
  union { s16x8 s; bf16x8 b; } u; u.s = v; return u.b;
}

// ---------------------------------------------------------------------------
// Kernel 0: cast weights fp32 -> bf16. [Wth 32768][Wph 32768][Wproj 65536].
// ---------------------------------------------------------------------------
__global__ __launch_bounds__(256) void cast_w_kernel(
    const float* __restrict__ Wth, const float* __restrict__ Wph,
    const float* __restrict__ Wpr, short* __restrict__ Wb) {
  int t = blockIdx.x * 256 + threadIdx.x;
  int i = t * 4;
  const float* src; int j;
  if (i < 32768)      { src = Wth; j = i; }
  else if (i < 65536) { src = Wph; j = i - 32768; }
  else                { src = Wpr; j = i - 65536; }
  float4 v = *(const float4*)(src + j);
  s16x4 o;
  o[0] = (short)f2bf(v.x); o[1] = (short)f2bf(v.y);
  o[2] = (short)f2bf(v.z); o[3] = (short)f2bf(v.w);
  *(s16x4*)(Wb + i) = o;
}

// ---------------------------------------------------------------------------
// Kernel 1 (MFMA): Q[s,e] = qscale * sum_c Wth[e,c] x[c,s]; K likewise.
// Emits bf16 x. Softmax log2-scale folded into Q. grid 512.
// ---------------------------------------------------------------------------
__global__ __launch_bounds__(256) void mix_kernel(
    const float* __restrict__ x, const short* __restrict__ Wb,
    short* __restrict__ Qg, short* __restrict__ Kg, short* __restrict__ Xb,
    float qscale) {
  __shared__ short lxT[32 * C_DIM];   // [s][c] bf16, swizzled, 16 KB
  int bid = blockIdx.x;
  int n = bid >> 7, s0 = (bid & 127) * 32;
  int tid = threadIdx.x;
  int wid = tid >> 6, lane = tid & 63, l15 = lane & 15, l4 = lane >> 4;

  { // stage x^T tile + emit Xb
    int cp = tid >> 1, su = tid & 1;
    const float* r0 = x + ((size_t)n * C_DIM + 2 * cp) * S_DIM + s0 + su * 16;
    const float* r1 = r0 + S_DIM;
    float a0[16], a1[16];
    #pragma unroll
    for (int j = 0; j < 4; ++j) {
      *(float4*)(a0 + 4 * j) = *(const float4*)(r0 + 4 * j);
      *(float4*)(a1 + 4 * j) = *(const float4*)(r1 + 4 * j);
    }
    short b0[16], b1[16];
    #pragma unroll
    for (int j = 0; j < 16; ++j) { b0[j] = (short)f2bf(a0[j]); b1[j] = (short)f2bf(a1[j]); }
    short* xb0 = Xb + ((size_t)n * C_DIM + 2 * cp) * S_DIM + s0 + su * 16;
    *(s16x8*)(xb0)             = *(s16x8*)(b0);
    *(s16x8*)(xb0 + 8)         = *(s16x8*)(b0 + 8);
    *(s16x8*)(xb0 + S_DIM)     = *(s16x8*)(b1);
    *(s16x8*)(xb0 + S_DIM + 8) = *(s16x8*)(b1 + 8);
    #pragma unroll
    for (int j = 0; j < 16; ++j) {
      int s = su * 16 + j;
      unsigned d = (unsigned)(unsigned short)b0[j] |
                   ((unsigned)(unsigned short)b1[j] << 16);
      *(unsigned*)((char*)lxT + s * 512 + ((4 * cp) ^ ((s & 7) << 4))) = d;
    }
  }
  __syncthreads();

  const short* Wq = Wb;
  const short* Wk = Wb + 32768;
  const f32x4 fzero = {0.f, 0.f, 0.f, 0.f};
  f32x4 accQ[2][2], accK[2][2];
  #pragma unroll
  for (int a = 0; a < 2; ++a)
    #pragma unroll
    for (int b = 0; b < 2; ++b) { accQ[a][b] = fzero; accK[a][b] = fzero; }

  #pragma unroll 2
  for (int kk = 0; kk < 8; ++kk) {
    bf16x8 bfr[2];
    #pragma unroll
    for (int nf = 0; nf < 2; ++nf) {
      int s = nf * 16 + l15;
      bfr[nf] = *(const bf16x8*)((char*)lxT + s * 512 +
                                 ((kk * 64 + l4 * 16) ^ ((s & 7) << 4)));
    }
    #pragma unroll
    for (int mf = 0; mf < 2; ++mf) {
      int e = wid * 32 + mf * 16 + l15;
      bf16x8 aq = *(const bf16x8*)(Wq + e * C_DIM + kk * 32 + l4 * 8);
      bf16x8 ak = *(const bf16x8*)(Wk + e * C_DIM + kk * 32 + l4 * 8);
      #pragma unroll
      for (int nf = 0; nf < 2; ++nf) {
        accQ[mf][nf] = __builtin_amdgcn_mfma_f32_16x16x32_bf16(aq, bfr[nf], accQ[mf][nf], 0, 0, 0);
        accK[mf][nf] = __builtin_amdgcn_mfma_f32_16x16x32_bf16(ak, bfr[nf], accK[mf][nf], 0, 0, 0);
      }
    }
  }

  #pragma unroll
  for (int mf = 0; mf < 2; ++mf) {
    #pragma unroll
    for (int nf = 0; nf < 2; ++nf) {
      int e = wid * 32 + mf * 16 + l4 * 4;
      int s = s0 + nf * 16 + l15;
      s16x4 pq, pk;
      #pragma unroll
      for (int r = 0; r < 4; ++r) {
        pq[r] = (short)f2bf(accQ[mf][nf][r] * qscale);
        pk[r] = (short)f2bf(accK[mf][nf][r]);
      }
      *(s16x4*)(Qg + ((size_t)n * S_DIM + s) * E_DIM + e) = pq;
      *(s16x4*)(Kg + ((size_t)n * S_DIM + s) * E_DIM + e) = pk;
    }
  }
}

// ---------------------------------------------------------------------------
// Kernel 2: flash attention, producer-consumer wave specialization.
// 512 threads: waves 0-3 = QK^T+exp+P (t-quarter each); waves 4-7 = PV
// (c-quarter each) + K staging. K,P double-buffered -> 1 barrier/window.
// V fragments read directly from global (L2). Q pre-scaled by log2e/sqrt(E).
// grid 256 (1 block/CU), XCD-swizzled so each n's K/V fits one XCD's L2.
// ---------------------------------------------------------------------------
__global__ __launch_bounds__(512, 2) void attn_kernel(
    const short* __restrict__ Qg, const short* __restrict__ Kg,
    const short* __restrict__ Xb, short* __restrict__ Yg) {
  __shared__ short lK[2 * 64 * E_DIM];   // 32 KB, dbuf, swizzled [t][e]
  __shared__ short lP[2 * 64 * 64];      // 16 KB, dbuf, swizzled [q][t]
  __shared__ float lsred[4 * 64];        // per-tq-wave row-sum partials

  int bid = blockIdx.x;
  // XCD swizzle: blocks land on XCD (bid&7); give each n two XCDs.
  int xcd = bid & 7;
  int n = xcd >> 1;
  int s0 = (((xcd & 1) << 5) + (bid >> 3)) * 64;

  int tid = threadIdx.x;
  int wid = tid >> 6, lane = tid & 63;
  int l15 = lane & 15, l4 = lane >> 4;

  const short* Kb = Kg + (size_t)n * S_DIM * E_DIM;
  const short* Vb = Xb + (size_t)n * (size_t)C_DIM * S_DIM;

  const f32x4 fzero = {0.f, 0.f, 0.f, 0.f};

  // ---------------- per-role persistent state ----------------
  bf16x8 qf[4][4];          // QKT waves: Q frags for all 64 q-rows
  float lsum[4][4];         // QKT waves: running softmax denominators
  f32x4 acc[4][4];          // PV waves: [qs][ct]
  s16x8 kpre[4];            // PV waves: staged K tile (next)
  s16x8 vpre[8];            // PV waves: V frags for current tile [kk*4+ct]

  int tq = wid;             // QKT: t-quarter
  int cq = wid - 4;         // PV:  c-quarter
  int idx = tid & 255;
  int kr = idx >> 4, kc = idx & 15;   // K staging assignment (PV waves)

  if (wid < 4) {
    #pragma unroll
    for (int qs = 0; qs < 4; ++qs) {
      const short* qp = Qg + ((size_t)n * S_DIM + s0 + qs * 16 + l15) * E_DIM + l4 * 8;
      #pragma unroll
      for (int ec = 0; ec < 4; ++ec) qf[qs][ec] = *(const bf16x8*)(qp + ec * 32);
    }
    #pragma unroll
    for (int a = 0; a < 4; ++a)
      #pragma unroll
      for (int b = 0; b < 4; ++b) lsum[a][b] = 0.f;
  } else {
    #pragma unroll
    for (int a = 0; a < 4; ++a)
      #pragma unroll
      for (int b = 0; b < 4; ++b) acc[a][b] = fzero;
    // stage K tile 0 into buf 0
    #pragma unroll
    for (int j = 0; j < 4; ++j)
      kpre[j] = *(const s16x8*)(Kb + (size_t)(kr + 16 * j) * E_DIM + kc * 8);
    #pragma unroll
    for (int j = 0; j < 4; ++j) {
      int r = kr + 16 * j;
      *(s16x8*)((char*)lK + r * 256 + ((kc * 16) ^ ((r & 7) << 4))) = kpre[j];
    }
    // prefetch K tile 1 and V tile 0
    #pragma unroll
    for (int j = 0; j < 4; ++j)
      kpre[j] = *(const s16x8*)(Kb + (size_t)(64 + kr + 16 * j) * E_DIM + kc * 8);
    #pragma unroll
    for (int kk = 0; kk < 2; ++kk)
      #pragma unroll
      for (int ct = 0; ct < 4; ++ct)
        vpre[kk * 4 + ct] = *(const s16x8*)(
            Vb + (size_t)(cq * 64 + ct * 16 + l15) * S_DIM + kk * 32 + l4 * 8);
  }
  __syncthreads();

  // ---------------- main pipeline: 65 windows, 1 barrier each ----------------
  for (int i = 0; i <= 64; ++i) {
    if (wid < 4) {
      if (i < 64) {
        const char* kb = (const char*)lK + (i & 1) * 16384;
        f32x4 sc[4] = {fzero, fzero, fzero, fzero};
        int trow = tq * 16 + l15;
        int swz = (trow & 7) << 4;
        #pragma unroll
        for (int ec = 0; ec < 4; ++ec) {
          bf16x8 kf = *(const bf16x8*)(kb + trow * 256 + ((ec * 64 + l4 * 16) ^ swz));
          #pragma unroll
          for (int qs = 0; qs < 4; ++qs)
            sc[qs] = __builtin_amdgcn_mfma_f32_16x16x32_bf16(qf[qs][ec], kf, sc[qs], 0, 0, 0);
        }
        char* pw = (char*)lP + (i & 1) * 8192;
        int t2 = (tq * 16 + l15) * 2;
        #pragma unroll
        for (int qs = 0; qs < 4; ++qs) {
          #pragma unroll
          for (int r = 0; r < 4; ++r) {
            float p = __builtin_amdgcn_exp2f(sc[qs][r]);
            lsum[qs][r] += p;
            int q = qs * 16 + l4 * 4 + r;
            union { float f; unsigned u; } cv; cv.f = p;
            *(unsigned short*)(pw + q * 128 + (t2 ^ ((q & 7) << 4))) =
                (unsigned short)(cv.u >> 16);
          }
        }
      }
    } else {
      if (i >= 1) {
        const char* pr = (const char*)lP + ((i & 1) ^ 1) * 8192;
        #pragma unroll
        for (int kk = 0; kk < 2; ++kk) {
          bf16x8 pf[4];
          #pragma unroll
          for (int qs = 0; qs < 4; ++qs) {
            int q = qs * 16 + l15;
            pf[qs] = *(const bf16x8*)(pr + q * 128 + ((kk * 64 + l4 * 16) ^ ((q & 7) << 4)));
          }
          #pragma unroll
          for (int ct = 0; ct < 4; ++ct) {
            bf16x8 vf = as_bf(vpre[kk * 4 + ct]);
            #pragma unroll
            for (int qs = 0; qs < 4; ++qs)
              acc[qs][ct] = __builtin_amdgcn_mfma_f32_16x16x32_bf16(pf[qs], vf, acc[qs][ct], 0, 0, 0);
          }
        }
        if (i < 64) {   // prefetch V tile i (consumed at window i+1)
          #pragma unroll
          for (int kk = 0; kk < 2; ++kk)
            #pragma unroll
            for (int ct = 0; ct < 4; ++ct)
              vpre[kk * 4 + ct] = *(const s16x8*)(
                  Vb + (size_t)(cq * 64 + ct * 16 + l15) * S_DIM + i * 64 + kk * 32 + l4 * 8);
        }
      }
      if (i <= 62) {    // commit K tile i+1 (in kpre) to buf (i+1)&1
        char* kw = (char*)lK + ((i + 1) & 1) * 16384;
        #pragma unroll
        for (int j = 0; j < 4; ++j) {
          int r = kr + 16 * j;
          *(s16x8*)(kw + r * 256 + ((kc * 16) ^ ((r & 7) << 4))) = kpre[j];
        }
      }
      if (i <= 61) {    // load K tile i+2
        #pragma unroll
        for (int j = 0; j < 4; ++j)
          kpre[j] = *(const s16x8*)(Kb + (size_t)((i + 2) * 64 + kr + 16 * j) * E_DIM + kc * 8);
      }
    }
    __syncthreads();
  }

  // ---------------- epilogue ----------------
  if (wid < 4) {
    #pragma unroll
    for (int qs = 0; qs < 4; ++qs)
      #pragma unroll
      for (int r = 0; r < 4; ++r) {
        float v = lsum[qs][r];
        v += __shfl_xor(v, 1); v += __shfl_xor(v, 2);
        v += __shfl_xor(v, 4); v += __shfl_xor(v, 8);
        if (l15 == 0) lsred[tq * 64 + qs * 16 + l4 * 4 + r] = v;
      }
  }
  __syncthreads();

  short* yst = lK;   // reuse 32 KB as y staging [64 q][256 c] swizzled
  if (wid >= 4) {
    #pragma unroll
    for (int qs = 0; qs < 4; ++qs) {
      #pragma unroll
      for (int r = 0; r < 4; ++r) {
        int q = qs * 16 + l4 * 4 + r;
        float tot = lsred[q] + lsred[64 + q] + lsred[128 + q] + lsred[192 + q];
        float rl = 1.0f / tot;
        #pragma unroll
        for (int ct = 0; ct < 4; ++ct) {
          int c = cq * 64 + ct * 16 + l15;
          union { float f; unsigned u; } cv; cv.f = acc[qs][ct][r] * rl;
          *(unsigned short*)((char*)yst + q * 512 + ((c * 2) ^ ((q & 7) << 4))) =
              (unsigned short)(cv.u >> 16);
        }
      }
    }
  }
  __syncthreads();

  int rr = tid >> 3, chb = tid & 7;
  #pragma unroll
  for (int it = 0; it < 4; ++it) {
    int ch = chb + 8 * it;
    s16x8 v = *(const s16x8*)((char*)yst + rr * 512 + ((ch * 16) ^ ((rr & 7) << 4)));
    *(s16x8*)(Yg + ((size_t)n * S_DIM + s0 + rr) * C_DIM + ch * 8) = v;
  }
}

// ---------------------------------------------------------------------------
// Kernel 3 (MFMA, zero LDS): out[o,s] = x[o,s] + sum_c Wp[o,c] y[s,c]
// ---------------------------------------------------------------------------
__global__ __launch_bounds__(256) void proj_kernel(
    const short* __restrict__ Yg, const short* __restrict__ Wpb,
    const float* __restrict__ x, float* __restrict__ out) {
  int bid = blockIdx.x;
  int n = bid >> 7, s0 = (bid & 127) * 32;
  int tid = threadIdx.x;
  int wid = tid >> 6, lane = tid & 63, l15 = lane & 15, l4 = lane >> 4;

  const f32x4 fzero = {0.f, 0.f, 0.f, 0.f};
  f32x4 acc[2][4];
  #pragma unroll
  for (int a = 0; a < 2; ++a)
    #pragma unroll
    for (int b = 0; b < 4; ++b) acc[a][b] = fzero;

  const short* ybase = Yg + (size_t)n * S_DIM * C_DIM;

  #pragma unroll 2
  for (int kk = 0; kk < 8; ++kk) {
    bf16x8 af[2];
    #pragma unroll
    for (int mf = 0; mf < 2; ++mf)
      af[mf] = *(const bf16x8*)(ybase + (size_t)(s0 + mf * 16 + l15) * C_DIM +
                                kk * 32 + l4 * 8);
    #pragma unroll
    for (int nf = 0; nf < 4; ++nf) {
      int o = wid * 64 + nf * 16 + l15;
      bf16x8 bfr = *(const bf16x8*)(Wpb + o * C_DIM + kk * 32 + l4 * 8);
      #pragma unroll
      for (int mf = 0; mf < 2; ++mf)
        acc[mf][nf] = __builtin_amdgcn_mfma_f32_16x16x32_bf16(af[mf], bfr, acc[mf][nf], 0, 0, 0);
    }
  }

  #pragma unroll
  for (int mf = 0; mf < 2; ++mf) {
    #pragma unroll
    for (int nf = 0; nf < 4; ++nf) {
      int o = wid * 64 + nf * 16 + l15;
      size_t idx = ((size_t)n * C_DIM + o) * (size_t)S_DIM + s0 + mf * 16 + l4 * 4;
      float4 xv = *(const float4*)(x + idx);
      float4 r;
      r.x = xv.x + acc[mf][nf][0];
      r.y = xv.y + acc[mf][nf][1];
      r.z = xv.z + acc[mf][nf][2];
      r.w = xv.w + acc[mf][nf][3];
      *(float4*)(out + idx) = r;
    }
  }
}

// ---------------------------------------------------------------------------
extern "C" void kernel_launch(void* const* d_in, const int* in_sizes, int n_in,
                              void* d_out, int out_size, void* d_ws, size_t ws_size,
                              hipStream_t stream) {
  const float* x   = (const float*)d_in[0];
  const float* Wth = (const float*)d_in[1];
  const float* Wph = (const float*)d_in[2];
  const float* Wpr = (const float*)d_in[3];
  float* out = (float*)d_out;

  short* q_ws  = (short*)d_ws;                              // 4 MB  [N,S,E]
  short* k_ws  = q_ws  + (size_t)4 * S_DIM * E_DIM;         // 4 MB  [N,S,E]
  short* xb_ws = k_ws  + (size_t)4 * S_DIM * E_DIM;         // 8 MB  [N,C,S]
  short* y_ws  = xb_ws + (size_t)4 * C_DIM * S_DIM;         // 8 MB  [N,S,C]
  short* wb_ws = y_ws  + (size_t)4 * S_DIM * C_DIM;         // 256 KB bf16 weights

  float qscale = 1.4426950408889634f / sqrtf(128.0f);       // log2(e)/sqrt(E)

  cast_w_kernel<<<128, 256, 0, stream>>>(Wth, Wph, Wpr, wb_ws);
  mix_kernel<<<512, 256, 0, stream>>>(x, wb_ws, q_ws, k_ws, xb_ws, qscale);
  attn_kernel<<<256, 512, 0, stream>>>(q_ws, k_ws, xb_ws, y_ws);
  proj_kernel<<<512, 256, 0, stream>>>(y_ws, wb_ws + 65536, x, out);
}